// Round 6
// baseline (42.653 us; speedup 1.0000x reference)
//
#include <hip/hip_runtime.h>

#define F 32
#define Dd 16
#define C 64
#define Kk 8
#define CLIPV (1.0f - 1e-6f)
#define TABSTRIDE 36      // floats per feature: 16 (a,b) pairs + bias + pad
#define K2 2.8853900817779268f  // 2*log2(e): tanh(z)=1-2/(2^(K2*z)+1)
#define NBLK 512          // 512 blocks x 4 waves x 64 rows = 131072 rows

typedef short v8s __attribute__((ext_vector_type(8)));
typedef float v4f __attribute__((ext_vector_type(4)));
typedef float v2f __attribute__((ext_vector_type(2)));

static __device__ inline unsigned cvtpk(float lo, float hi) {
    unsigned r;
    asm("v_cvt_pk_bf16_f32 %0, %1, %2" : "=v"(r) : "v"(lo), "v"(hi));
    return r;
}

// Fully register-resident streaming design:
//  - lane (r16,h) evaluates features f = 4q+h (q=0..7) of row r16 of its tile,
//    producing the MFMA A-fragment for K-step q directly in registers
//    (A[row=r16][k=h*8+j] = basis[r16][f=4q+h][chebk=j])
//  - B (all 64 classes) persistent in 128 VGPRs: B[k=h*8+j][col=r16] for
//    step (q,nt) = coeff[nt*16+r16][4q+h][j]
//  - no basis LDS, no per-tile barriers; each wave streams 4 independent
//    16-row tiles (grid-stride by construction, contiguous 64 rows per wave)
__global__ __launch_bounds__(256, 2) void qkan_kernel(
    const float* __restrict__ X,        // [B,32]
    const float* __restrict__ phases,   // [16]
    const float* __restrict__ lcu_w,    // [32,16]
    const float* __restrict__ sscale,   // [32]
    const float* __restrict__ sbias,    // [32]
    const float* __restrict__ coeff,    // [64,32,8]
    const float* __restrict__ kbias,    // [64]
    float* __restrict__ out)            // [B,64]
{
    __shared__ float s_tab[F * TABSTRIDE];  // folded Clenshaw table, 4608 B

    const int tid = threadIdx.x;
    const int lane = tid & 63;
    const int wu = __builtin_amdgcn_readfirstlane(tid >> 6);
    const int h = lane >> 4;
    const int r16 = lane & 15;

    const int row00 = (blockIdx.x * 4 + wu) * 64;  // this wave's 64 rows

    // ---- X prefetch for tile 0: xq[m] = X[row00+r16][4m+h] ----
    float xq[8];
    {
        const float* xp = X + (size_t)(row00 + r16) * F + h;
#pragma unroll
        for (int m = 0; m < 8; ++m) xq[m] = xp[4 * m];
    }

    // ---- persistent B fragments (64KB coeff, L2-resident after first touch) ----
    v8s Bfr[8][4];
#pragma unroll
    for (int q = 0; q < 8; ++q) {
#pragma unroll
        for (int nt = 0; nt < 4; ++nt) {
            const float* gp = coeff + ((size_t)((nt * 16 + r16) * F + 4 * q + h) * Kk);
            const float4 g0 = *reinterpret_cast<const float4*>(gp);
            const float4 g1 = *reinterpret_cast<const float4*>(gp + 4);
            union { unsigned u[4]; v8s v; } bb;
            bb.u[0] = cvtpk(g0.x, g0.y);
            bb.u[1] = cvtpk(g0.z, g0.w);
            bb.u[2] = cvtpk(g1.x, g1.y);
            bb.u[3] = cvtpk(g1.z, g1.w);
            Bfr[q][nt] = bb.v;
        }
    }
    const float bias0 = kbias[r16];
    const float bias1 = kbias[16 + r16];
    const float bias2 = kbias[32 + r16];
    const float bias3 = kbias[48 + r16];

    // ---- fold table per block (overlaps the load latency above) ----
    // K2*z_f(x) = sum_d a_fd T_d(x) + sqrt(1-x^2) * sum_d b_fd U_{d-1}(x) + fb_f
    // layout s_tab[f*36 + {2d: a_{d+1}, 2d+1: b_{d+1}, 32: fb}]
    for (int idx = tid; idx < F * Dd; idx += 256) {
        const int f = idx >> 4, d = idx & 15;
        float asum = 0.f;
#pragma unroll
        for (int dd = 0; dd < Dd; ++dd) asum += fabsf(lcu_w[f * Dd + dd]);
        const float sc = K2 * sscale[f] / (asum + 1e-6f);
        float sp, cp;
        __sincosf(phases[d], &sp, &cp);
        const float wv = lcu_w[f * Dd + d];
        s_tab[f * TABSTRIDE + 2 * d]     = sc * wv * cp;   // a_{d+1}
        s_tab[f * TABSTRIDE + 2 * d + 1] = -sc * wv * sp;  // b_{d+1}
        if (d == 0) s_tab[f * TABSTRIDE + 32] = K2 * sbias[f];
    }
    __syncthreads();  // the only barrier

#pragma unroll
    for (int it = 0; it < 4; ++it) {
        const int row0 = row00 + it * 16;

        // prefetch next tile's X (dead on last iter)
        float xn[8];
        if (it < 3) {
            const float* xp = X + (size_t)(row0 + 16 + r16) * F + h;
#pragma unroll
            for (int m = 0; m < 8; ++m) xn[m] = xp[4 * m];
        }

        v4f acc0 = {0.f, 0.f, 0.f, 0.f};
        v4f acc1 = {0.f, 0.f, 0.f, 0.f};
        v4f acc2 = {0.f, 0.f, 0.f, 0.f};
        v4f acc3 = {0.f, 0.f, 0.f, 0.f};

#pragma unroll
        for (int q = 0; q < 8; ++q) {
            const int f = 4 * q + h;  // this lane's feature for K-step q
            const float* tfp = s_tab + f * TABSTRIDE;
            const v2f* tf2 = reinterpret_cast<const v2f*>(tfp);
            const float fb = tfp[32];
            const float x = fminf(fmaxf(xq[q], -CLIPV), CLIPV);
            const float s1 = sqrtf(fmaxf(__builtin_fmaf(-x, x, 1.f), 0.f));
            const float tx = x + x;
            const v2f tx2 = {tx, tx};
            // paired Clenshaw: .x = T-chain (coeff a), .y = U-chain (coeff b)
            v2f w = {0.f, 0.f}, wp = {0.f, 0.f};
#pragma unroll
            for (int j = 15; j >= 0; --j) {
                const v2f wn = (tf2[j] - wp) + tx2 * w;  // v_pk_add + v_pk_fma
                wp = w;
                w = wn;
            }
            float z = fb - wp.x;
            z = __builtin_fmaf(x, w.x, z);
            z = __builtin_fmaf(s1, w.y, z);
            // tanh via exp2 (K2 pre-folded): t = 1 - 2/(2^z + 1)
            float e;
            asm("v_exp_f32 %0, %1" : "=v"(e) : "v"(z));
            const float rr = __builtin_amdgcn_rcpf(e + 1.f);
            const float t = __builtin_fmaf(-2.f, rr, 1.f);
            // Chebyshev basis T_0..T_7 -> A-fragment in registers
            const float t2 = t + t;
            const float b1 = t;
            const float b2 = t2 * b1 - 1.f;
            const float b3 = t2 * b2 - b1;
            const float b4 = t2 * b3 - b2;
            const float b5 = t2 * b4 - b3;
            const float b6 = t2 * b5 - b4;
            const float b7 = t2 * b6 - b5;
            union { unsigned u[4]; v8s v; } pa;
            pa.u[0] = cvtpk(1.f, b1);
            pa.u[1] = cvtpk(b2, b3);
            pa.u[2] = cvtpk(b4, b5);
            pa.u[3] = cvtpk(b6, b7);
            acc0 = __builtin_amdgcn_mfma_f32_16x16x32_bf16(pa.v, Bfr[q][0], acc0, 0, 0, 0);
            acc1 = __builtin_amdgcn_mfma_f32_16x16x32_bf16(pa.v, Bfr[q][1], acc1, 0, 0, 0);
            acc2 = __builtin_amdgcn_mfma_f32_16x16x32_bf16(pa.v, Bfr[q][2], acc2, 0, 0, 0);
            acc3 = __builtin_amdgcn_mfma_f32_16x16x32_bf16(pa.v, Bfr[q][3], acc3, 0, 0, 0);
        }

        // ---- stores: C[row=h*4+i][col] ; 16-lane contiguous 64B segments ----
        const int orow = row0 + h * 4;
#pragma unroll
        for (int i = 0; i < 4; ++i) {
            float* op = out + (size_t)(orow + i) * C + r16;
            op[0]  = acc0[i] + bias0;
            op[16] = acc1[i] + bias1;
            op[32] = acc2[i] + bias2;
            op[48] = acc3[i] + bias3;
        }

        if (it < 3) {
#pragma unroll
            for (int m = 0; m < 8; ++m) xq[m] = xn[m];
        }
    }
}

extern "C" void kernel_launch(void* const* d_in, const int* in_sizes, int n_in,
                              void* d_out, int out_size, void* d_ws, size_t ws_size,
                              hipStream_t stream) {
    const float* X  = (const float*)d_in[0];
    const float* ph = (const float*)d_in[1];
    const float* lw = (const float*)d_in[2];
    const float* ss = (const float*)d_in[3];
    const float* sb = (const float*)d_in[4];
    const float* kc = (const float*)d_in[5];
    const float* kb = (const float*)d_in[6];
    float* out = (float*)d_out;
    qkan_kernel<<<dim3(NBLK), dim3(256), 0, stream>>>(X, ph, lw, ss, sb, kc, kb, out);
}

// Round 7
// 27.594 us; speedup vs baseline: 1.5458x; 1.5458x over previous
//
#include <hip/hip_runtime.h>

#define F 32
#define Dd 16
#define C 64
#define Kk 8
#define CLIPV (1.0f - 1e-6f)
#define CHUNKU 536        // ushorts per k-chunk: 64 rows * 8 bf16 + pad -> 1072B (mod 128 = 48)
#define K2 2.8853900817779268f  // 2*log2(e): tanh(z)=1-2/(2^(K2*z)+1)
#define NBLK 1024
#define MT 2              // row-tiles of 64 per block

typedef short v8s __attribute__((ext_vector_type(8)));
typedef float v4f __attribute__((ext_vector_type(4)));
typedef float v2f __attribute__((ext_vector_type(2)));

static __device__ inline unsigned cvtpk(float lo, float hi) {
    unsigned r;
    asm("v_cvt_pk_bf16_f32 %0, %1, %2" : "=v"(r) : "v"(lo), "v"(hi));
    return r;
}

// Phase-1 is feature-major: thread (fe = tid&31, rg = tid>>5) evaluates feature
// fe for rows rg*8..rg*8+7 of the 64-row tile. The folded Clenshaw table for fe
// (16 (a,b) pairs + bias) is computed ONCE into VGPRs -> zero LDS/table reads
// per eval, 8-way row ILP per thread, coalesced X reads (lanes 0..31 = one row).
// Phase-2 (MFMA) is unchanged from the r5 design: wave wu owns classes
// [16wu,16wu+16), A-fragments read from the chunk-major LDS basis.
__global__ __launch_bounds__(256, 4) void qkan_kernel(
    const float* __restrict__ X,        // [B,32]
    const float* __restrict__ phases,   // [16]
    const float* __restrict__ lcu_w,    // [32,16]
    const float* __restrict__ sscale,   // [32]
    const float* __restrict__ sbias,    // [32]
    const float* __restrict__ coeff,    // [64,32,8]
    const float* __restrict__ kbias,    // [64]
    float* __restrict__ out)            // [B,64]
{
    // chunk-major basis: chunk f holds 64 rows x 8 bf16 (16B/row); stride 1072B
    // -> both phase-1 writes and phase-2 reads touch every bank exactly 8x (min)
    __shared__ unsigned short s_basis[F * CHUNKU];   // 34304 B

    const int tid = threadIdx.x;
    const int lane = tid & 63;
    const int wu = __builtin_amdgcn_readfirstlane(tid >> 6);
    const int h = lane >> 4;
    const int r16 = lane & 15;
    const int fe = tid & 31;   // eval feature
    const int rg = tid >> 5;   // eval row-group (8 rows)

    const int rb0 = blockIdx.x * (MT * 64);

    // ---- X prefetch for tile 0: xq[m] = X[rb0+rg*8+m][fe] (coalesced) ----
    float xq[8];
    {
        const float* xp = X + (size_t)(rb0 + rg * 8) * F + fe;
#pragma unroll
        for (int m = 0; m < 8; ++m) xq[m] = xp[m * F];
    }

    // ---- fold Clenshaw table for feature fe into VGPRs (once per kernel) ----
    // K2*z(x) = sum_d a_d T_d(x) + sqrt(1-x^2) * sum_d b_d U_{d-1}(x) + fbias
    v2f cc[16];
    float fbias;
    {
        const float* lwf = lcu_w + fe * Dd;
        float wv[16];
        float asum = 0.f;
#pragma unroll
        for (int d = 0; d < Dd; ++d) {
            wv[d] = lwf[d];
            asum += fabsf(wv[d]);
        }
        const float sc = K2 * sscale[fe] / (asum + 1e-6f);
#pragma unroll
        for (int d = 0; d < Dd; ++d) {
            float sp, cp;
            __sincosf(phases[d], &sp, &cp);
            cc[d][0] = sc * wv[d] * cp;    // a_{d+1}
            cc[d][1] = -sc * wv[d] * sp;   // b_{d+1}
        }
        fbias = K2 * sbias[fe];
    }

    // ---- B fragments: wave wu owns classes [16wu,16wu+16) ----
    // MFMA step q, lane quarter h, regs j hold phys kappa=(4q+h)*8+j,
    // i.e. f=4q+h, cheb-k=j (same lane<->k map on A and B => K-perm invariant)
    v8s Bfr[8];
    const int cidx = wu * 16 + r16;
#pragma unroll
    for (int q = 0; q < 8; ++q) {
        const float* gp = coeff + ((size_t)(cidx * F + 4 * q + h) * Kk);
        const float4 g0 = *reinterpret_cast<const float4*>(gp);
        const float4 g1 = *reinterpret_cast<const float4*>(gp + 4);
        union { unsigned u[4]; v8s v; } bb;
        bb.u[0] = cvtpk(g0.x, g0.y);
        bb.u[1] = cvtpk(g0.z, g0.w);
        bb.u[2] = cvtpk(g1.x, g1.y);
        bb.u[3] = cvtpk(g1.z, g1.w);
        Bfr[q] = bb.v;
    }
    const float biasreg = kbias[cidx];

    for (int mt = 0; mt < MT; ++mt) {
        const int row_base = rb0 + mt * 64;
        if (mt) __syncthreads();  // previous phase-2 reads done before overwrite

        // prefetch next tile's X
        float xn[8];
        if (mt + 1 < MT) {
            const float* xp = X + (size_t)(row_base + 64 + rg * 8) * F + fe;
#pragma unroll
            for (int m = 0; m < 8; ++m) xn[m] = xp[m * F];
        }

        // ---- phase 1: 8 independent row-evals of feature fe, table in VGPRs ----
#pragma unroll
        for (int m = 0; m < 8; ++m) {
            const int row = rg * 8 + m;
            const float x = fminf(fmaxf(xq[m], -CLIPV), CLIPV);
            const float s1 = sqrtf(fmaxf(__builtin_fmaf(-x, x, 1.f), 0.f));
            const float tx = x + x;
            const v2f tx2 = {tx, tx};
            // paired Clenshaw: .x = T-chain (coeff a), .y = U-chain (coeff b)
            v2f w = {0.f, 0.f}, wp = {0.f, 0.f};
#pragma unroll
            for (int j = 15; j >= 0; --j) {
                const v2f wn = (cc[j] - wp) + tx2 * w;  // v_pk_add + v_pk_fma
                wp = w;
                w = wn;
            }
            float z = fbias - wp[0];
            z = __builtin_fmaf(x, w[0], z);
            z = __builtin_fmaf(s1, w[1], z);
            // tanh via exp2 (K2 pre-folded): t = 1 - 2/(2^z + 1)
            float e;
            asm("v_exp_f32 %0, %1" : "=v"(e) : "v"(z));
            const float rr = __builtin_amdgcn_rcpf(e + 1.f);
            const float t = __builtin_fmaf(-2.f, rr, 1.f);
            // Chebyshev basis T_0..T_7 -> one b128 LDS write
            const float t2 = t + t;
            const float b1 = t;
            const float b2 = t2 * b1 - 1.f;
            const float b3 = t2 * b2 - b1;
            const float b4 = t2 * b3 - b2;
            const float b5 = t2 * b4 - b3;
            const float b6 = t2 * b5 - b4;
            const float b7 = t2 * b6 - b5;
            uint4 pk;
            pk.x = cvtpk(1.f, b1);
            pk.y = cvtpk(b2, b3);
            pk.z = cvtpk(b4, b5);
            pk.w = cvtpk(b6, b7);
            *reinterpret_cast<uint4*>(&s_basis[fe * CHUNKU + row * 8]) = pk;
        }
        __syncthreads();

        // ---- phase 2: MFMA, wave wu computes classes [16wu,16wu+16) for 64 rows ----
#pragma unroll
        for (int t = 0; t < 4; ++t) {
            v4f acc = {0.f, 0.f, 0.f, 0.f};
#pragma unroll
            for (int q = 0; q < 8; ++q) {
                const v8s a = *reinterpret_cast<const v8s*>(
                    &s_basis[(4 * q + h) * CHUNKU + (t * 16 + r16) * 8]);
                acc = __builtin_amdgcn_mfma_f32_16x16x32_bf16(a, Bfr[q], acc, 0, 0, 0);
            }
            const int row0 = row_base + t * 16 + h * 4;
#pragma unroll
            for (int i = 0; i < 4; ++i) {
                out[(size_t)(row0 + i) * C + cidx] = acc[i] + biasreg;
            }
        }

        if (mt + 1 < MT) {
#pragma unroll
            for (int m = 0; m < 8; ++m) xq[m] = xn[m];
        }
    }
}

extern "C" void kernel_launch(void* const* d_in, const int* in_sizes, int n_in,
                              void* d_out, int out_size, void* d_ws, size_t ws_size,
                              hipStream_t stream) {
    const float* X  = (const float*)d_in[0];
    const float* ph = (const float*)d_in[1];
    const float* lw = (const float*)d_in[2];
    const float* ss = (const float*)d_in[3];
    const float* sb = (const float*)d_in[4];
    const float* kc = (const float*)d_in[5];
    const float* kb = (const float*)d_in[6];
    float* out = (float*)d_out;
    qkan_kernel<<<dim3(NBLK), dim3(256), 0, stream>>>(X, ph, lw, ss, sb, kc, kb, out);
}